// Round 2
// baseline (584.654 us; speedup 1.0000x reference)
//
#include <hip/hip_runtime.h>
#include <math.h>

// ---------------- constants ----------------
#define P1H 66
#define P1W 208
#define P1PLANE (P1H * P1W)   // 13728 floats per (b,ic) plane, zero-padded border

// ws layout (bytes):
//   p1p   : 0           .. 112,459,776   (64*32*66*208 f32)
//   p2    : 112,459,776 .. 164,888,576   (64*64*32*100 f32)
//   -- after K2, p1p region is dead; f64 tail buffers reuse it --
//   hm    : 0           ..  3,276,800    (64*64*100 f64)
//   hproj : 3,276,800   .. 16,384,000    (64*100*256 f64)
//   curs  : 16,384,000  .. 22,937,600    (64*50*256 f64)
//   cur1  : 22,937,600  .. 29,491,200    (64*50*256 f64)
//   cur2  : 29,491,200  .. 32,768,000    (64*50*128 f64)
//   s2f   : 32,768,000  .. 34,406,400    (64*50*128 f32)

// ---------------- K0: zero the padded border of p1p ----------------
__global__ __launch_bounds__(256) void k0_border(float* __restrict__ p1p) {
  int plane = blockIdx.x;                       // b*32+ic, 2048 planes
  float* base = p1p + (size_t)plane * P1PLANE;
  for (int i = threadIdx.x; i < 544; i += 256) {
    int r, c;
    if (i < 208)      { r = 0;            c = i; }
    else if (i < 416) { r = 65;           c = i - 208; }
    else if (i < 480) { r = i - 416 + 1;  c = 0; }
    else              { r = i - 480 + 1;  c = 201; }
    base[r * P1W + c] = 0.f;
  }
}

// ---------------- K1: conv1(3x3,SAME) + bn1 + relu + maxpool2 ----------------
__global__ __launch_bounds__(256) void k1_conv1(
    const float* __restrict__ x,  const float* __restrict__ c1w,
    const float* __restrict__ c1b, const float* __restrict__ g1,
    const float* __restrict__ b1, const float* __restrict__ m1,
    const float* __restrict__ v1, float* __restrict__ p1p) {
  __shared__ float tile[18][67];
  __shared__ float scale[32], shift[32];
  int wx = blockIdx.x, hy = blockIdx.y, b = blockIdx.z;
  int tid = threadIdx.x;
  int gy0 = hy * 16 - 1, gx0 = wx * 64 - 1;
  const float* xb = x + (size_t)b * 128 * 400;
  for (int i = tid; i < 18 * 66; i += 256) {
    int r = i / 66, c = i - r * 66;
    int gr = gy0 + r, gc = gx0 + c;
    float v = 0.f;
    if (gr >= 0 && gr < 128 && gc >= 0 && gc < 400) v = xb[gr * 400 + gc];
    tile[r][c] = v;
  }
  if (tid < 32) {
    double s = (double)g1[tid] / sqrt((double)v1[tid] + 1e-5);
    scale[tid] = (float)s;
    shift[tid] = (float)(((double)c1b[tid] - (double)m1[tid]) * s + (double)b1[tid]);
  }
  __syncthreads();
  int tx = tid & 31, ty = tid >> 5;
  int pw = wx * 32 + tx;         // pooled col < 200
  int ph = hy * 8 + ty;          // pooled row < 64
  if (pw >= 200) return;
  float in[4][4];
#pragma unroll
  for (int r = 0; r < 4; ++r)
#pragma unroll
    for (int c = 0; c < 4; ++c) in[r][c] = tile[2 * ty + r][2 * tx + c];
  for (int ch = 0; ch < 32; ++ch) {
    float s00 = 0, s01 = 0, s10 = 0, s11 = 0;
#pragma unroll
    for (int ky = 0; ky < 3; ++ky)
#pragma unroll
      for (int kx = 0; kx < 3; ++kx) {
        float w = c1w[ch * 9 + ky * 3 + kx];   // uniform -> s_load
        s00 = fmaf(w, in[ky][kx],     s00);
        s01 = fmaf(w, in[ky][kx + 1], s01);
        s10 = fmaf(w, in[ky + 1][kx],     s10);
        s11 = fmaf(w, in[ky + 1][kx + 1], s11);
      }
    float sc = scale[ch], sh = shift[ch];
    float y00 = fmaxf(fmaf(sc, s00, sh), 0.f);
    float y01 = fmaxf(fmaf(sc, s01, sh), 0.f);
    float y10 = fmaxf(fmaf(sc, s10, sh), 0.f);
    float y11 = fmaxf(fmaf(sc, s11, sh), 0.f);
    float r = fmaxf(fmaxf(y00, y01), fmaxf(y10, y11));
    p1p[((size_t)(b * 32 + ch) * P1H + (ph + 1)) * P1W + (pw + 1)] = r;
  }
}

// ---------------- K2: conv2(3x3,SAME) + bn2 + relu + maxpool2 ----------------
// lane = oc(64); wave = one 2x4-pooled (4x8 pre-pool) tile.
// acc = 32 VGPRs (was 64 -> AGPR overflow last round); launch_bounds(256,6)
// for 24 waves/CU to hide HBM-miss latency of the uniform s_load input rows.
__global__ __launch_bounds__(256, 6) void k2_conv2(
    const float* __restrict__ p1p, const float* __restrict__ c2w,
    const float* __restrict__ c2b, const float* __restrict__ g2,
    const float* __restrict__ b2, const float* __restrict__ m2,
    const float* __restrict__ v2, float* __restrict__ p2) {
  int b = blockIdx.z;
  int wid = __builtin_amdgcn_readfirstlane((int)(threadIdx.x >> 6));
  int lane = threadIdx.x & 63;                  // = oc
  int widx = blockIdx.x * 4 + wid;              // 0..399 tile id
  int ty = widx / 25, tx = widx - ty * 25;      // ty 0..15, tx 0..24 (uniform)
  int r0 = ty * 4, c0 = tx * 8;                 // pre-pool origin
  const float* ipbase = p1p + (size_t)(b * 32) * P1PLANE + r0 * P1W + c0;
  float acc[4][8];
#pragma unroll
  for (int i = 0; i < 4; ++i)
#pragma unroll
    for (int j = 0; j < 8; ++j) acc[i][j] = 0.f;

  for (int ic = 0; ic < 32; ++ic) {
    float wv[9];
    const float* wp = c2w + ((lane * 32) + ic) * 9;
#pragma unroll
    for (int j = 0; j < 9; ++j) wv[j] = wp[j];
    const float* ip = ipbase + (size_t)ic * P1PLANE;
#pragma unroll
    for (int l = 0; l < 6; ++l) {               // local input rows
      float srow[10];
#pragma unroll
      for (int c = 0; c < 10; ++c) srow[c] = ip[l * P1W + c];  // uniform -> s_load
#pragma unroll
      for (int o = 0; o < 4; ++o) {             // output rows using row l
        int ky = l - o;
        if (ky >= 0 && ky <= 2) {
#pragma unroll
          for (int xo = 0; xo < 8; ++xo) {
            acc[o][xo] = fmaf(srow[xo + 0], wv[ky * 3 + 0], acc[o][xo]);
            acc[o][xo] = fmaf(srow[xo + 1], wv[ky * 3 + 1], acc[o][xo]);
            acc[o][xo] = fmaf(srow[xo + 2], wv[ky * 3 + 2], acc[o][xo]);
          }
        }
      }
    }
  }
  // epilogue: bn affine + relu + 2x2 maxpool, store 2x4 pooled
  int oc = lane;
  double sd = (double)g2[oc] / sqrt((double)v2[oc] + 1e-5);
  float sc = (float)sd;
  float sh = (float)(((double)c2b[oc] - (double)m2[oc]) * sd + (double)b2[oc]);
#pragma unroll
  for (int py = 0; py < 2; ++py)
#pragma unroll
    for (int px = 0; px < 4; ++px) {
      float q00 = fmaxf(fmaf(sc, acc[2 * py][2 * px],         sh), 0.f);
      float q01 = fmaxf(fmaf(sc, acc[2 * py][2 * px + 1],     sh), 0.f);
      float q10 = fmaxf(fmaf(sc, acc[2 * py + 1][2 * px],     sh), 0.f);
      float q11 = fmaxf(fmaf(sc, acc[2 * py + 1][2 * px + 1], sh), 0.f);
      float r = fmaxf(fmaxf(q00, q01), fmaxf(q10, q11));
      p2[((size_t)(b * 64 + oc) * 32 + (ty * 2 + py)) * 100 + (tx * 4 + px)] = r;
    }
}

// ---------------- K3: mean over freq (H=32), f32 -> f64 ----------------
__global__ __launch_bounds__(256) void k3_mean(const float* __restrict__ p2,
                                               double* __restrict__ hm) {
  int idx = blockIdx.x * 256 + threadIdx.x;      // 409600 = 64*64*100
  int xcol = idx % 100;
  int bc = idx / 100;
  const float* p = p2 + (size_t)bc * 3200 + xcol;
  double s = 0.0;
#pragma unroll
  for (int h = 0; h < 32; ++h) s += (double)p[h * 100];
  hm[idx] = s * (1.0 / 32.0);
}

// ---------------- block reduction helper (256 threads) ----------------
__device__ __forceinline__ double block_reduce_sum_256(double v, double* sbuf) {
#pragma unroll
  for (int off = 32; off > 0; off >>= 1) v += __shfl_down(v, off, 64);
  int lane = threadIdx.x & 63, wid = threadIdx.x >> 6;
  __syncthreads();
  if (lane == 0) sbuf[wid] = v;
  __syncthreads();
  return sbuf[0] + sbuf[1] + sbuf[2] + sbuf[3];
}

// ---------------- K4: channel_proj + LayerNorm (4 rows/block) ----------------
// activations read as wave-uniform s_load (hm is L2-resident); pw element
// loaded once per 4 rows -> 4x less weight traffic.
__global__ __launch_bounds__(256) void k4_proj_ln(
    const double* __restrict__ hm, const float* __restrict__ pw,
    const float* __restrict__ pb, const float* __restrict__ plg,
    const float* __restrict__ plb, double* __restrict__ hproj) {
  __shared__ double sbuf[4];
  int bt0 = blockIdx.x * 4;             // 4 | 100 -> same b for all 4 rows
  int b = bt0 / 100, t0 = bt0 - b * 100;
  int k = threadIdx.x;
  double accv[4];
  double pbk = (double)pb[k];
#pragma unroll
  for (int r = 0; r < 4; ++r) accv[r] = pbk;
  const double* hmb = hm + (size_t)b * 64 * 100 + t0;
#pragma unroll 4
  for (int c = 0; c < 64; ++c) {
    double w = (double)pw[c * 256 + k];
    const double* hp = hmb + c * 100;   // uniform, 4 contiguous f64
    accv[0] = fma(hp[0], w, accv[0]);
    accv[1] = fma(hp[1], w, accv[1]);
    accv[2] = fma(hp[2], w, accv[2]);
    accv[3] = fma(hp[3], w, accv[3]);
  }
  double gk = (double)plg[k], bk = (double)plb[k];
#pragma unroll
  for (int r = 0; r < 4; ++r) {
    double mean = block_reduce_sum_256(accv[r], sbuf) * (1.0 / 256.0);
    double d = accv[r] - mean;
    double var = block_reduce_sum_256(d * d, sbuf) * (1.0 / 256.0);
    double inv = 1.0 / sqrt(var + 1e-5);
    hproj[(size_t)(bt0 + r) * 256 + k] = d * inv * gk + bk;
  }
}

// ---------------- K5a: interp(x2 avg) + LayerNorm ----------------
__global__ __launch_bounds__(256) void k5a_interp_ln(
    const double* __restrict__ hproj, const float* __restrict__ ing,
    const float* __restrict__ inb, double* __restrict__ curs) {
  __shared__ double sbuf[4];
  int bs = blockIdx.x;                  // b*50 + s
  int b = bs / 50, st = bs - b * 50;
  int k = threadIdx.x;
  const double* hp = hproj + (size_t)(b * 100 + 2 * st) * 256;
  double xk = 0.5 * (hp[k] + hp[256 + k]);   // src = 2s+0.5 -> avg of pair
  double mean = block_reduce_sum_256(xk, sbuf) * (1.0 / 256.0);
  double d = xk - mean;
  double var = block_reduce_sum_256(d * d, sbuf) * (1.0 / 256.0);
  double inv = 1.0 / sqrt(var + 1e-5);
  curs[(size_t)bs * 256 + k] = d * inv * (double)ing[k] + (double)inb[k];
}

// ---------------- K5b: fc1 GEMM, 8 rows/block ----------------
__global__ __launch_bounds__(256) void k5b_fc1(
    const double* __restrict__ curs, const float* __restrict__ fc1w,
    const float* __restrict__ fc1b, double* __restrict__ cur1) {
  int row0 = blockIdx.x * 8;            // 400 blocks
  int k = threadIdx.x;
  double accv[8];
  double bk = (double)fc1b[k];
#pragma unroll
  for (int r = 0; r < 8; ++r) accv[r] = bk;
  const double* ab = curs + (size_t)row0 * 256;
#pragma unroll 4
  for (int c = 0; c < 256; ++c) {
    double w = (double)fc1w[c * 256 + k];
#pragma unroll
    for (int r = 0; r < 8; ++r)
      accv[r] = fma(ab[(size_t)r * 256 + c], w, accv[r]);   // uniform s_load
  }
#pragma unroll
  for (int r = 0; r < 8; ++r) cur1[(size_t)(row0 + r) * 256 + k] = accv[r];
}

// ---------------- K6: LIF1 scan -> spike_record (spread over 256 blocks) ----
__global__ __launch_bounds__(64) void k6_lif1(
    const double* __restrict__ cur1, const float* __restrict__ beta1p,
    const float* __restrict__ thr1p, float* __restrict__ dout) {
  int b = blockIdx.x >> 2;
  int k = ((blockIdx.x & 3) << 6) + threadIdx.x;
  double beta = (double)beta1p[0];
  beta = beta < 0.0 ? 0.0 : (beta > 1.0 ? 1.0 : beta);
  double thr = (double)thr1p[0];
  double mem = 0.0;
  float* srec = dout + 128;             // spike_record after logits
  for (int t = 0; t < 50; ++t) {
    double c = cur1[(size_t)(b * 50 + t) * 256 + k];
    mem = beta * mem + c - ((mem > thr) ? thr : 0.0);   // reset uses prev mem
    srec[(size_t)(b * 50 + t) * 256 + k] = (mem > thr) ? 1.0f : 0.0f;
  }
}

// ---------------- K7: fc2 GEMM on spikes, 8 rows/block ----------------
__global__ __launch_bounds__(128) void k7_fc2(
    const float* __restrict__ dout, const float* __restrict__ fc2w,
    const float* __restrict__ fc2b, double* __restrict__ cur2) {
  int row0 = blockIdx.x * 8;            // 400 blocks
  int j = threadIdx.x;
  const float* srec = dout + 128;
  double accv[8];
  double bj = (double)fc2b[j];
#pragma unroll
  for (int r = 0; r < 8; ++r) accv[r] = bj;
#pragma unroll 4
  for (int c = 0; c < 256; ++c) {
    double w = (double)fc2w[c * 128 + j];
#pragma unroll
    for (int r = 0; r < 8; ++r)
      accv[r] = fma((double)srec[(size_t)(row0 + r) * 256 + c], w, accv[r]);  // uniform s_load
  }
#pragma unroll
  for (int r = 0; r < 8; ++r) cur2[(size_t)(row0 + r) * 128 + j] = accv[r];
}

// ---------------- K8a: LIF2 scans (parallel over b,j) ----------------
__global__ __launch_bounds__(64) void k8a_lif2(
    const double* __restrict__ cur2, const float* __restrict__ beta2p,
    const float* __restrict__ thr2p, float* __restrict__ s2f) {
  int idx = blockIdx.x * 64 + threadIdx.x;   // 8192 = 64*128
  int b = idx >> 7, j = idx & 127;
  double beta2 = (double)beta2p[0];
  beta2 = beta2 < 0.0 ? 0.0 : (beta2 > 1.0 ? 1.0 : beta2);
  double thr2 = (double)thr2p[0];
  double m2 = 0.0;
  for (int t = 0; t < 50; ++t) {
    double c2 = cur2[(size_t)(b * 50 + t) * 128 + j];
    m2 = beta2 * m2 + c2 - ((m2 > thr2) ? thr2 : 0.0);
    s2f[(size_t)(b * 50 + t) * 128 + j] = (m2 > thr2) ? 1.0f : 0.0f;
  }
}

// ---------------- K8b: fc_out per timestep + LIF3 scan + logits ----------
__global__ __launch_bounds__(64) void k8b_out(
    const float* __restrict__ s2f, const float* __restrict__ fcow,
    const float* __restrict__ fcob, const float* __restrict__ beta3p,
    const float* __restrict__ thr3p, float* __restrict__ dout) {
  __shared__ double c3s[50][2];
  int b = blockIdx.x, t = threadIdx.x;
  if (t < 50) {
    double c30 = (double)fcob[0], c31 = (double)fcob[1];
    const float* sp = s2f + (size_t)(b * 50 + t) * 128;
#pragma unroll 4
    for (int jj = 0; jj < 128; ++jj) {
      double s = (double)sp[jj];
      c30 = fma(s, (double)fcow[jj * 2 + 0], c30);
      c31 = fma(s, (double)fcow[jj * 2 + 1], c31);
    }
    c3s[t][0] = c30; c3s[t][1] = c31;
  }
  __syncthreads();
  if (t == 0) {
    double beta3 = (double)beta3p[0];
    beta3 = beta3 < 0.0 ? 0.0 : (beta3 > 1.0 ? 1.0 : beta3);
    double thr3 = (double)thr3p[0];
    double mo0 = 0.0, mo1 = 0.0, l0 = 0.0, l1 = 0.0;
    for (int tt = 0; tt < 50; ++tt) {
      mo0 = beta3 * mo0 + c3s[tt][0] - ((mo0 > thr3) ? thr3 : 0.0);
      mo1 = beta3 * mo1 + c3s[tt][1] - ((mo1 > thr3) ? thr3 : 0.0);
      l0 += mo0; l1 += mo1;
    }
    dout[b * 2 + 0] = (float)l0; dout[b * 2 + 1] = (float)l1;
  }
}

// ---------------- launch ----------------
extern "C" void kernel_launch(void* const* d_in, const int* in_sizes, int n_in,
                              void* d_out, int out_size, void* d_ws, size_t ws_size,
                              hipStream_t stream) {
  const float* x    = (const float*)d_in[0];
  const float* c1w  = (const float*)d_in[1];
  const float* c1b  = (const float*)d_in[2];
  const float* bn1g = (const float*)d_in[3];
  const float* bn1b = (const float*)d_in[4];
  const float* bn1m = (const float*)d_in[5];
  const float* bn1v = (const float*)d_in[6];
  const float* c2w  = (const float*)d_in[7];
  const float* c2b  = (const float*)d_in[8];
  const float* bn2g = (const float*)d_in[9];
  const float* bn2b = (const float*)d_in[10];
  const float* bn2m = (const float*)d_in[11];
  const float* bn2v = (const float*)d_in[12];
  const float* pw   = (const float*)d_in[13];
  const float* pb   = (const float*)d_in[14];
  const float* plg  = (const float*)d_in[15];
  const float* plb  = (const float*)d_in[16];
  const float* ing  = (const float*)d_in[17];
  const float* inb  = (const float*)d_in[18];
  const float* fc1w = (const float*)d_in[19];
  const float* fc1b = (const float*)d_in[20];
  const float* fc2w = (const float*)d_in[21];
  const float* fc2b = (const float*)d_in[22];
  const float* fcow = (const float*)d_in[23];
  const float* fcob = (const float*)d_in[24];
  const float* beta1 = (const float*)d_in[25];
  const float* thr1  = (const float*)d_in[26];
  const float* beta2 = (const float*)d_in[27];
  const float* thr2  = (const float*)d_in[28];
  const float* beta3 = (const float*)d_in[29];
  const float* thr3  = (const float*)d_in[30];

  char* ws = (char*)d_ws;
  float*  p1p   = (float*)ws;
  float*  p2    = (float*)(ws + 112459776ULL);
  double* hm    = (double*)ws;                       // reuses p1p (dead after K2)
  double* hproj = (double*)(ws + 3276800ULL);
  double* curs  = (double*)(ws + 16384000ULL);
  double* cur1  = (double*)(ws + 22937600ULL);
  double* cur2  = (double*)(ws + 29491200ULL);
  float*  s2f   = (float*)(ws + 32768000ULL);
  float* dout = (float*)d_out;

  k0_border<<<dim3(2048), 256, 0, stream>>>(p1p);
  k1_conv1<<<dim3(7, 8, 64), 256, 0, stream>>>(x, c1w, c1b, bn1g, bn1b, bn1m, bn1v, p1p);
  k2_conv2<<<dim3(100, 1, 64), 256, 0, stream>>>(p1p, c2w, c2b, bn2g, bn2b, bn2m, bn2v, p2);
  k3_mean<<<dim3(1600), 256, 0, stream>>>(p2, hm);
  k4_proj_ln<<<dim3(1600), 256, 0, stream>>>(hm, pw, pb, plg, plb, hproj);
  k5a_interp_ln<<<dim3(3200), 256, 0, stream>>>(hproj, ing, inb, curs);
  k5b_fc1<<<dim3(400), 256, 0, stream>>>(curs, fc1w, fc1b, cur1);
  k6_lif1<<<dim3(256), 64, 0, stream>>>(cur1, beta1, thr1, dout);
  k7_fc2<<<dim3(400), 128, 0, stream>>>(dout, fc2w, fc2b, cur2);
  k8a_lif2<<<dim3(128), 64, 0, stream>>>(cur2, beta2, thr2, s2f);
  k8b_out<<<dim3(64), 64, 0, stream>>>(s2f, fcow, fcob, beta3, thr3, dout);
}